// Round 7
// baseline (314.822 us; speedup 1.0000x reference)
//
#include <hip/hip_runtime.h>
#include <hip/hip_bf16.h>
#include <cstdint>
#include <cstddef>

// Problem: B=64, L=2048, E=1024, A=512
#define BB   64
#define LL   2048
#define ED   1024
#define AD   512
#define BM   128          // l-rows per block
#define NCH  (LL / BM)    // 16 chunks per batch row
#define NT   32           // 32 K-tiles of BK=32

typedef short  short8  __attribute__((ext_vector_type(8)));
typedef float  f32x4   __attribute__((ext_vector_type(4)));

__device__ __forceinline__ unsigned short f2bf(float x) {
  unsigned u = __float_as_uint(x);
  u += 0x7FFFu + ((u >> 16) & 1u);
  return (unsigned short)(u >> 16);
}

// pack 8 fp32 -> 8 bf16 via v_cvt_pk_bf16_f32
__device__ __forceinline__ short8 cvt8(f32x4 lo, f32x4 hi) {
  union { short8 s; unsigned u[4]; } r;
  asm("v_cvt_pk_bf16_f32 %0, %1, %2" : "=v"(r.u[0]) : "v"(lo[0]), "v"(lo[1]));
  asm("v_cvt_pk_bf16_f32 %0, %1, %2" : "=v"(r.u[1]) : "v"(lo[2]), "v"(lo[3]));
  asm("v_cvt_pk_bf16_f32 %0, %1, %2" : "=v"(r.u[2]) : "v"(hi[0]), "v"(hi[1]));
  asm("v_cvt_pk_bf16_f32 %0, %1, %2" : "=v"(r.u[3]) : "v"(hi[2]), "v"(hi[3]));
  return r.s;
}

#define GLOAD_LDS16(gp, lp)                                                        \
  __builtin_amdgcn_global_load_lds(                                                \
      (const __attribute__((address_space(1))) unsigned int*)(gp),                 \
      (__attribute__((address_space(3))) unsigned int*)(lp), 16, 0, 0)

// ---------------- kernel 0: prep ----------------
// blocks 0..63   : dec_proj row b = dec[b] @ W_dec + b_dec
// blocks 64..191 : pack W_enc fp32 -> bf16 in the fused kernel's LDS image order:
//   o = ks*16384 + cblk*512 + kg*128 + r*8 + j ; k = ks*32+kg*8+j, col = cblk*16+r
__global__ __launch_bounds__(512) void prep_kernel(
    const float* __restrict__ W_enc, const float* __restrict__ dec,
    const float* __restrict__ W_dec, const float* __restrict__ b_dec,
    unsigned short* __restrict__ Wb, float* __restrict__ dp) {
  const int blk = blockIdx.x, t = threadIdx.x;
  if (blk < BB) {
    const float* drow = dec + blk * ED;
    float a0 = 0.f, a1 = 0.f, a2 = 0.f, a3 = 0.f;
    for (int k = 0; k < ED; k += 4) {
      a0 = fmaf(drow[k],     W_dec[(k)     * AD + t], a0);
      a1 = fmaf(drow[k + 1], W_dec[(k + 1) * AD + t], a1);
      a2 = fmaf(drow[k + 2], W_dec[(k + 2) * AD + t], a2);
      a3 = fmaf(drow[k + 3], W_dec[(k + 3) * AD + t], a3);
    }
    dp[blk * AD + t] = (a0 + a1) + (a2 + a3) + b_dec[t];
  } else {
    const int base = (blk - BB) * 4096;
#pragma unroll
    for (int ii = 0; ii < 8; ii++) {
      const int o    = base + ii * 512 + t;
      const int ks   = o >> 14;
      const int cblk = (o >> 9) & 31;
      const int kg   = (o >> 7) & 3;
      const int r    = (o >> 3) & 15;
      const int j    = o & 7;
      const int k    = ks * 32 + kg * 8 + j;
      const int c    = cblk * 16 + r;
      Wb[o] = f2bf(W_enc[k * AD + c]);
    }
  }
}

// ---------------- kernel 1: fused GEMM + tanh-score + softmax partials ----------
// grid (NCH, BB), 512 threads = 8 waves (2M x 4N), wave tile 64 x 128.
// 8-PHASE-TEMPLATE SCHEDULE (T3+T4): 32 K-tiles x 4 phases. Per phase:
//   {2 ds_read_b128 (B subtile) [+4 A reads at p0] + 1 B global_load_lds (t+2)
//    [+ A gloads at p0 / A cvt+ds_write at p3] ; s_barrier ; lgkmcnt(0) ;
//    setprio(1) ; 8 MFMA quadrant ; setprio(0) ; s_barrier}.
// B triple-buffered (2-deep prefetch); A reg-staged 2-deep in 2 named sets.
// ONE counted vmcnt(6) per K-tile (= tile's own 6 in-flight issues); never 0.
__global__ __launch_bounds__(512, 2) void fused_kernel(
    const float* __restrict__ sem, const unsigned short* __restrict__ Wb,
    const float* __restrict__ dp, const float* __restrict__ b_enc,
    const float* __restrict__ Wf,
    float* __restrict__ raw_scores,
    float* __restrict__ ws_ms, float* __restrict__ ws_o) {

  __shared__ unsigned short Ab[2][4096];     // [buf][rblk(8)][kg(4)][16][8]  16 KB
  __shared__ unsigned short Bb[3][16384];    // [buf][cblk(32)][kg(4)][16][8] 96 KB

  const int t    = threadIdx.x;
  const int lane = t & 63;
  const int wave = t >> 6;
  const int wm   = wave >> 2;   // 0..1 row half
  const int wn   = wave & 3;    // 0..3 col quarter
  const int b    = blockIdx.y;
  const int chunk= blockIdx.x;
  const int l0   = chunk * BM;

  // staging mapping
  const int srow = t >> 2;      // 0..127
  const int skg  = t & 3;       // 0..3
  const float* aptr = sem + ((size_t)(b * LL + l0 + srow)) * ED + skg * 8;
  const unsigned short* bsrc = Wb + t * 8;   // + ks*16384 + i*4096
  const int awr = (srow >> 4) * 512 + skg * 128 + (srow & 15) * 8;

  // frag read bases (shorts): wave-contiguous 1 KB ds_read_b128, conflict-free
  const int arow = lane & 15;
  const int akg  = lane >> 4;
  const int afr  = wm * 2048 + lane * 8;     // + mf*512
  const int bfr  = wn * 4096 + lane * 8;     // + nf*512

  f32x4 acc[4][8];
#pragma unroll
  for (int i = 0; i < 4; i++)
#pragma unroll
    for (int j = 0; j < 8; j++) acc[i][j] = (f32x4)0.f;

  // ---- prologue: B(0)->Bb0, B(1)->Bb1, A(0)->regs->cvt->Ab0, A(1)->qA ----
#pragma unroll
  for (int i = 0; i < 4; i++)
    GLOAD_LDS16(bsrc + i * 4096, &Bb[0][i * 4096 + t * 8]);
#pragma unroll
  for (int i = 0; i < 4; i++)
    GLOAD_LDS16(bsrc + 16384 + i * 4096, &Bb[1][i * 4096 + t * 8]);
  f32x4 tA0 = *(const f32x4*)(aptr);
  f32x4 tA1 = *(const f32x4*)(aptr + 4);
  f32x4 qA0 = *(const f32x4*)(aptr + 32);
  f32x4 qA1 = *(const f32x4*)(aptr + 36);
  f32x4 pA0, pA1;
  {
    short8 aw = cvt8(tA0, tA1);    // auto-waits counted vmcnt (qA stays in flight)
    *(short8*)&Ab[0][awr] = aw;
  }
  asm volatile("s_waitcnt vmcnt(2) lgkmcnt(0)" ::: "memory");
  __builtin_amdgcn_sched_barrier(0);
  __builtin_amdgcn_s_barrier();

#define PHASE_MFMA(E, O, bE, bO)                                                   \
    __builtin_amdgcn_s_setprio(1);                                                 \
    acc[0][E] = __builtin_amdgcn_mfma_f32_16x16x32_bf16(av0, bE, acc[0][E], 0,0,0);\
    acc[1][E] = __builtin_amdgcn_mfma_f32_16x16x32_bf16(av1, bE, acc[1][E], 0,0,0);\
    acc[2][E] = __builtin_amdgcn_mfma_f32_16x16x32_bf16(av2, bE, acc[2][E], 0,0,0);\
    acc[3][E] = __builtin_amdgcn_mfma_f32_16x16x32_bf16(av3, bE, acc[3][E], 0,0,0);\
    acc[0][O] = __builtin_amdgcn_mfma_f32_16x16x32_bf16(av0, bO, acc[0][O], 0,0,0);\
    acc[1][O] = __builtin_amdgcn_mfma_f32_16x16x32_bf16(av1, bO, acc[1][O], 0,0,0);\
    acc[2][O] = __builtin_amdgcn_mfma_f32_16x16x32_bf16(av2, bO, acc[2][O], 0,0,0);\
    acc[3][O] = __builtin_amdgcn_mfma_f32_16x16x32_bf16(av3, bO, acc[3][O], 0,0,0);\
    __builtin_amdgcn_s_setprio(0);

#define BARRIER_LGKM                                                               \
    __builtin_amdgcn_s_barrier();                                                  \
    asm volatile("s_waitcnt lgkmcnt(0)" ::: "memory");                             \
    __builtin_amdgcn_sched_barrier(0);

  // ITER: tile ks. Reads Ab[AR], Bb[BR]; stages B(ks+2)->Bb[BW], A(ks+2)->(LA0,LA1);
  //       cvt (CA0,CA1)=A(ks+1) -> Ab[AW]. End-of-tile counted s_waitcnt vmcnt(VM).
#define ITER(ks, BR, BW, AR, AW, CA0, CA1, LA0, LA1, STG, CVT, VM)                 \
  {                                                                                \
    /* ---- p0 ---- */                                                             \
    short8 av0 = *(const short8*)&Ab[AR][afr];                                     \
    short8 av1 = *(const short8*)&Ab[AR][afr + 512];                               \
    short8 av2 = *(const short8*)&Ab[AR][afr + 1024];                              \
    short8 av3 = *(const short8*)&Ab[AR][afr + 1536];                              \
    short8 b0 = *(const short8*)&Bb[BR][bfr];                                      \
    short8 b1 = *(const short8*)&Bb[BR][bfr + 512];                                \
    if (STG) {                                                                     \
      GLOAD_LDS16(bsrc + ((ks) + 2) * 16384, &Bb[BW][t * 8]);                      \
      const float* ap = aptr + ((ks) + 2) * 32;                                    \
      LA0 = *(const f32x4*)(ap);                                                   \
      LA1 = *(const f32x4*)(ap + 4);                                               \
    }                                                                              \
    BARRIER_LGKM                                                                   \
    PHASE_MFMA(0, 1, b0, b1)                                                       \
    __builtin_amdgcn_s_barrier();                                                  \
    /* ---- p1 ---- */                                                             \
    short8 b2 = *(const short8*)&Bb[BR][bfr + 1024];                               \
    short8 b3 = *(const short8*)&Bb[BR][bfr + 1536];                               \
    if (STG) GLOAD_LDS16(bsrc + ((ks) + 2) * 16384 + 4096, &Bb[BW][4096 + t * 8]); \
    BARRIER_LGKM                                                                   \
    PHASE_MFMA(2, 3, b2, b3)                                                       \
    __builtin_amdgcn_s_barrier();                                                  \
    /* ---- p2 ---- */                                                             \
    short8 b4 = *(const short8*)&Bb[BR][bfr + 2048];                               \
    short8 b5 = *(const short8*)&Bb[BR][bfr + 2560];                               \
    if (STG) GLOAD_LDS16(bsrc + ((ks) + 2) * 16384 + 8192, &Bb[BW][8192 + t * 8]); \
    BARRIER_LGKM                                                                   \
    PHASE_MFMA(4, 5, b4, b5)                                                       \
    __builtin_amdgcn_s_barrier();                                                  \
    /* ---- p3 ---- */                                                             \
    short8 b6 = *(const short8*)&Bb[BR][bfr + 3072];                               \
    short8 b7 = *(const short8*)&Bb[BR][bfr + 3584];                               \
    if (STG) GLOAD_LDS16(bsrc + ((ks) + 2) * 16384 + 12288, &Bb[BW][12288 + t * 8]);\
    if (CVT) {                                                                     \
      short8 aw = cvt8(CA0, CA1);  /* auto counted vmcnt: t+2 loads stay */        \
      *(short8*)&Ab[AW][awr] = aw;                                                 \
    }                                                                              \
    BARRIER_LGKM                                                                   \
    PHASE_MFMA(6, 7, b6, b7)                                                       \
    asm volatile("s_waitcnt vmcnt(" #VM ")" ::: "memory");                         \
    __builtin_amdgcn_sched_barrier(0);                                             \
    __builtin_amdgcn_s_barrier();                                                  \
  }

  for (int base = 0; base < 30; base += 6) {
    ITER(base + 0, 0, 2, 0, 1, qA0, qA1, pA0, pA1, 1, 1, 6)
    ITER(base + 1, 1, 0, 1, 0, pA0, pA1, qA0, qA1, 1, 1, 6)
    ITER(base + 2, 2, 1, 0, 1, qA0, qA1, pA0, pA1, 1, 1, 6)
    ITER(base + 3, 0, 2, 1, 0, pA0, pA1, qA0, qA1, 1, 1, 6)
    ITER(base + 4, 1, 0, 0, 1, qA0, qA1, pA0, pA1, 1, 1, 6)
    ITER(base + 5, 2, 1, 1, 0, pA0, pA1, qA0, qA1, 1, 1, 6)
  }
  ITER(30, 0, 0, 0, 1, qA0, qA1, pA0, pA1, 0, 1, 0)
  ITER(31, 1, 0, 1, 0, pA0, pA1, qA0, qA1, 0, 0, 0)
#undef ITER
#undef BARRIER_LGKM
#undef PHASE_MFMA

  // ---- epilogue smem carved out of Bb (all B reads done past final barrier) ----
  float* eb = (float*)&Bb[0][0];
  float (*sc_part)[4]   = (float (*)[4])eb;            // 128*4
  float* scores_lds     = eb + 512;                    // 128
  float* weight         = eb + 640;                    // 128
  float (*o_lds)[AD]    = (float (*)[AD])(eb + 768);   // 2*512
  float* bcv            = eb + 1792;                   // 2

  // ---- add b_enc, tanh-score, online-softmax partials ----
  float dpv[8], wfv[8], bev[8];
#pragma unroll
  for (int nf = 0; nf < 8; nf++) {
    const int c = wn * 128 + nf * 16 + arow;
    dpv[nf] = dp[b * AD + c];
    wfv[nf] = Wf[c];
    bev[nf] = b_enc[c];
  }
#pragma unroll
  for (int mf = 0; mf < 4; mf++) {
#pragma unroll
    for (int r = 0; r < 4; r++) {
      float p = 0.f;
#pragma unroll
      for (int nf = 0; nf < 8; nf++) {
        float e = acc[mf][nf][r] + bev[nf];
        acc[mf][nf][r] = e;                      // keep enc_proj (+b_enc) for o-accum
        float x = e + dpv[nf];
        float ex = __expf(2.f * x);              // tanh via exp
        float th = 1.f - 2.f / (ex + 1.f);
        p = fmaf(th, wfv[nf], p);
      }
      p += __shfl_xor(p, 1); p += __shfl_xor(p, 2);
      p += __shfl_xor(p, 4); p += __shfl_xor(p, 8);
      if (arow == 0) sc_part[wm * 64 + mf * 16 + akg * 4 + r][wn] = p;
    }
  }
  __syncthreads();

  if (t < BM) {
    float s = sc_part[t][0] + sc_part[t][1] + sc_part[t][2] + sc_part[t][3];
    scores_lds[t] = s;
    raw_scores[(size_t)b * LL + l0 + t] = s;     // raw; finalize normalizes in place
  }
  __syncthreads();
  if (t < 64) {
    float m = fmaxf(scores_lds[t], scores_lds[t + 64]);
#pragma unroll
    for (int off = 1; off < 64; off <<= 1) m = fmaxf(m, __shfl_xor(m, off));
    if (t == 0) bcv[0] = m;
  }
  __syncthreads();
  const float m_c = bcv[0];
  if (t < BM) weight[t] = __expf(scores_lds[t] - m_c);
  __syncthreads();
  if (t < 64) {
    float s = weight[t] + weight[t + 64];
#pragma unroll
    for (int off = 1; off < 64; off <<= 1) s += __shfl_xor(s, off);
    if (t == 0) bcv[1] = s;
  }

  float wv[4][4];
#pragma unroll
  for (int mf = 0; mf < 4; mf++)
#pragma unroll
    for (int r = 0; r < 4; r++) wv[mf][r] = weight[wm * 64 + mf * 16 + akg * 4 + r];
#pragma unroll
  for (int nf = 0; nf < 8; nf++) {
    float cp = 0.f;
#pragma unroll
    for (int mf = 0; mf < 4; mf++)
#pragma unroll
      for (int r = 0; r < 4; r++) cp = fmaf(wv[mf][r], acc[mf][nf][r], cp);
    cp += __shfl_xor(cp, 16);
    cp += __shfl_xor(cp, 32);
    if (lane < 16) o_lds[wm][wn * 128 + nf * 16 + lane] = cp;
  }
  __syncthreads();
  if (t < AD)
    ws_o[((size_t)b * NCH + chunk) * AD + t] = o_lds[0][t] + o_lds[1][t];
  if (t == 0) {
    ws_ms[(b * NCH + chunk) * 2]     = m_c;
    ws_ms[(b * NCH + chunk) * 2 + 1] = bcv[1];
  }
}

// ---------------- kernel 2: finalize (merge chunk partials, normalize) ----------
__global__ __launch_bounds__(256) void finalize_kernel(
    const float* __restrict__ ws_ms, const float* __restrict__ ws_o,
    float* __restrict__ out0, float* __restrict__ outS) {
  const int b = blockIdx.x, t = threadIdx.x;
  float ms[NCH], ss[NCH];
  float M = -1e30f;
#pragma unroll
  for (int i = 0; i < NCH; i++) {
    ms[i] = ws_ms[(b * NCH + i) * 2];
    ss[i] = ws_ms[(b * NCH + i) * 2 + 1];
    M = fmaxf(M, ms[i]);
  }
  float S = 0.f, w[NCH];
#pragma unroll
  for (int i = 0; i < NCH; i++) { w[i] = __expf(ms[i] - M); S = fmaf(ss[i], w[i], S); }
  const float invS = 1.f / S;
  for (int c = t; c < AD; c += 256) {
    float a = 0.f;
#pragma unroll
    for (int i = 0; i < NCH; i++) a = fmaf(ws_o[((size_t)b * NCH + i) * AD + c], w[i], a);
    out0[b * AD + c] = a * invS;
  }
  for (int l = t; l < LL; l += 256) {
    float r = outS[(size_t)b * LL + l];
    outS[(size_t)b * LL + l] = __expf(r - M) * invS;
  }
}

extern "C" void kernel_launch(void* const* d_in, const int* in_sizes, int n_in,
                              void* d_out, int out_size, void* d_ws, size_t ws_size,
                              hipStream_t stream) {
  const float* sem    = (const float*)d_in[0];
  const float* dec    = (const float*)d_in[1];
  const float* W_enc  = (const float*)d_in[2];
  const float* b_enc  = (const float*)d_in[3];
  const float* W_dec  = (const float*)d_in[4];
  const float* b_dec  = (const float*)d_in[5];
  const float* W_full = (const float*)d_in[6];
  // d_in[7] = b_full: constant shift, cancels in softmax.

  float* out0 = (float*)d_out;            // att_output [64][512]
  float* outS = out0 + BB * AD;           // att_scores [64][2048]

  char* ws = (char*)d_ws;
  unsigned short* Wb = (unsigned short*)ws;                          // 1 MB bf16 packed W_enc
  float* dpw   = (float*)(ws + (1 << 20));                           // 128 KB dec_proj+b_dec
  float* ws_ms = (float*)(ws + (1 << 20) + (128 << 10));             // 8 KB (m,s) per chunk
  float* ws_o  = (float*)(ws + (1 << 20) + (136 << 10));             // 2 MB o partials

  prep_kernel<<<BB + 128, 512, 0, stream>>>(W_enc, dec, W_dec, b_dec, Wb, dpw);
  dim3 g1(NCH, BB);
  fused_kernel<<<g1, 512, 0, stream>>>(sem, Wb, dpw, b_enc, W_full, outS, ws_ms, ws_o);
  finalize_kernel<<<BB, 256, 0, stream>>>(ws_ms, ws_o, out0, outS);
}

// Round 9
// 278.880 us; speedup vs baseline: 1.1289x; 1.1289x over previous
//
#include <hip/hip_runtime.h>
#include <hip/hip_bf16.h>
#include <cstdint>
#include <cstddef>

// Problem: B=64, L=2048, E=1024, A=512
#define BB   64
#define LL   2048
#define ED   1024
#define AD   512
#define BM   64           // l-rows per block (block = 64 x 512, 8 waves of 64x64)
#define NCH  (LL / BM)    // 32 chunks per batch row
#define KST  32           // 32 K-steps of BK=32

typedef short  short4v __attribute__((ext_vector_type(4)));
typedef short  short8  __attribute__((ext_vector_type(8)));
typedef float  f32x4   __attribute__((ext_vector_type(4)));

__device__ __forceinline__ unsigned short f2bf(float x) {
  unsigned u = __float_as_uint(x);
  u += 0x7FFFu + ((u >> 16) & 1u);
  return (unsigned short)(u >> 16);
}

// pack 4 fp32 -> 4 bf16 (RNE) via v_cvt_pk_bf16_f32
__device__ __forceinline__ short4v cvt4(f32x4 v) {
  union { short4v s; unsigned u[2]; } r;
  asm("v_cvt_pk_bf16_f32 %0, %1, %2" : "=v"(r.u[0]) : "v"(v[0]), "v"(v[1]));
  asm("v_cvt_pk_bf16_f32 %0, %1, %2" : "=v"(r.u[1]) : "v"(v[2]), "v"(v[3]));
  return r.s;
}

#define GLOAD_LDS16(gp, lp)                                                        \
  __builtin_amdgcn_global_load_lds(                                                \
      (const __attribute__((address_space(1))) unsigned int*)(gp),                 \
      (__attribute__((address_space(3))) unsigned int*)(lp), 16, 0, 0)

// ---------------- kernel 0: prep ----------------
// blocks 0..63   : dec_proj row b = dec[b] @ W_dec + b_dec
// blocks 64..191 : pack W_enc fp32 -> bf16 in the fused kernel's LDS image order:
//   o = ks*16384 + cblk*512 + kg*128 + r*8 + j ; k = ks*32+kg*8+j, col = cblk*16+r
__global__ __launch_bounds__(512) void prep_kernel(
    const float* __restrict__ W_enc, const float* __restrict__ dec,
    const float* __restrict__ W_dec, const float* __restrict__ b_dec,
    unsigned short* __restrict__ Wb, float* __restrict__ dp) {
  const int blk = blockIdx.x, t = threadIdx.x;
  if (blk < BB) {
    const float* drow = dec + blk * ED;
    float a0 = 0.f, a1 = 0.f, a2 = 0.f, a3 = 0.f;
    for (int k = 0; k < ED; k += 4) {
      a0 = fmaf(drow[k],     W_dec[(k)     * AD + t], a0);
      a1 = fmaf(drow[k + 1], W_dec[(k + 1) * AD + t], a1);
      a2 = fmaf(drow[k + 2], W_dec[(k + 2) * AD + t], a2);
      a3 = fmaf(drow[k + 3], W_dec[(k + 3) * AD + t], a3);
    }
    dp[blk * AD + t] = (a0 + a1) + (a2 + a3) + b_dec[t];
  } else {
    const int base = (blk - BB) * 4096;
#pragma unroll
    for (int ii = 0; ii < 8; ii++) {
      const int o    = base + ii * 512 + t;
      const int ks   = o >> 14;
      const int cblk = (o >> 9) & 31;
      const int kg   = (o >> 7) & 3;
      const int r    = (o >> 3) & 15;
      const int j    = o & 7;
      const int k    = ks * 32 + kg * 8 + j;
      const int c    = cblk * 16 + r;
      Wb[o] = f2bf(W_enc[k * AD + c]);
    }
  }
}

// ---------------- kernel 1: fused GEMM + tanh-score + softmax partials ----------
// grid (NCH=32, BB), 512 threads = 8 waves (1M x 8N), wave tile 64 x 64.
// acc[4][4] = 64 regs; __launch_bounds__(512,4) caps VGPR at 128 ->
// 4 waves/SIMD = TWO independent co-resident blocks per CU (LDS 72 KB x2 = 144).
// A LDS layout [rblk(4)][kg(4)][16][8]: rblk stride 512, kg stride 128 (R8 bug
// was 2048/512 strides -> frag reads walked out of Ab into Bb).
__global__ __launch_bounds__(512, 4) void fused_kernel(
    const float* __restrict__ sem, const unsigned short* __restrict__ Wb,
    const float* __restrict__ dp, const float* __restrict__ b_enc,
    const float* __restrict__ Wf,
    float* __restrict__ raw_scores,
    float* __restrict__ ws_ms, float* __restrict__ ws_o) {

  __shared__ unsigned short Ab[2][2048];     // [buf][rblk(4)][kg(4)][16][8]   8 KB
  __shared__ unsigned short Bb[2][16384];    // [buf][cblk(32)][kg(4)][16][8] 64 KB

  const int t    = threadIdx.x;
  const int lane = t & 63;
  const int wn   = t >> 6;      // 0..7 col eighth (64 cols each)
  const int b    = blockIdx.y;
  const int chunk= blockIdx.x;
  const int l0   = chunk * BM;

  // A staging: thread -> (row srow, k-quad skg); 1 f32x4 load, 1 ds_write_b64
  const int srow = t >> 3;      // 0..63
  const int skg  = t & 7;       // 0..7 (k = skg*4 .. skg*4+3)
  const float* aptr = sem + ((size_t)(b * LL + l0 + srow)) * ED + skg * 4;
  // k = skg*4+q -> kg = skg>>1, j = (skg&1)*4+q ; rblk = srow>>4, r = srow&15
  const int awr = (srow >> 4) * 512 + (skg >> 1) * 128 + (srow & 15) * 8 + (skg & 1) * 4;

  const unsigned short* bsrc = Wb + t * 8;   // + ks*16384 + i*4096

  // frag read bases (shorts): wave-contiguous ds_read_b128
  const int arow = lane & 15;
  const int akg  = lane >> 4;
  const int afr  = lane * 8;                 // + mf*512  (A: [rblk=mf][kg][16][8])
  const int bfr  = wn * 2048 + lane * 8;     // + nf*512  (B: 4 cblks per wave)

  f32x4 acc[4][4];
#pragma unroll
  for (int i = 0; i < 4; i++)
#pragma unroll
    for (int j = 0; j < 4; j++) acc[i][j] = (f32x4)0.f;

  // ---- prologue: B(0) DMAs, A(0)->cvt->Ab0, A(1) in flight ----
#pragma unroll
  for (int i = 0; i < 4; i++)
    GLOAD_LDS16(bsrc + i * 4096, &Bb[0][i * 4096 + t * 8]);
  f32x4 pA = *(const f32x4*)(aptr);
  f32x4 qA = *(const f32x4*)(aptr + 32);
  *(short4v*)&Ab[0][awr] = cvt4(pA);         // auto-waits pA; qA stays in flight
  asm volatile("s_waitcnt vmcnt(1) lgkmcnt(0)" ::: "memory");
  __builtin_amdgcn_sched_barrier(0);
  __builtin_amdgcn_s_barrier();

  // ITER(ks): reads Ab[cb], Bb[cb]; stages B(ks+1)->Bb[nb], cvt A(ks+1)(=CA)->Ab[nb],
  //           loads A(ks+2)->LA. End: counted vmcnt (keep A-load in flight) + barrier.
#define ITER(ks, CA, LA)                                                           \
  {                                                                                \
    const int cb = (ks) & 1, nb = ((ks) + 1) & 1;                                  \
    if ((ks) + 1 < KST) {                                                          \
      const unsigned short* bs = bsrc + ((ks) + 1) * 16384;                        \
      _Pragma("unroll")                                                            \
      for (int i = 0; i < 4; i++)                                                  \
        GLOAD_LDS16(bs + i * 4096, &Bb[nb][i * 4096 + t * 8]);                     \
    }                                                                              \
    __builtin_amdgcn_sched_barrier(0);  /* pin: B DMAs before A cvt/load */        \
    if ((ks) + 1 < KST)                                                            \
      *(short4v*)&Ab[nb][awr] = cvt4(CA);  /* auto vmcnt(4): B DMAs stay */        \
    if ((ks) + 2 < KST)                                                            \
      LA = *(const f32x4*)(aptr + ((ks) + 2) * 32);                                \
    short8 av[4], bv[4];                                                           \
    _Pragma("unroll")                                                              \
    for (int mf = 0; mf < 4; mf++)                                                 \
      av[mf] = *(const short8*)&Ab[cb][afr + mf * 512];                            \
    _Pragma("unroll")                                                              \
    for (int nf = 0; nf < 4; nf++)                                                 \
      bv[nf] = *(const short8*)&Bb[cb][bfr + nf * 512];                            \
    __builtin_amdgcn_s_setprio(1);                                                 \
    _Pragma("unroll")                                                              \
    for (int mf = 0; mf < 4; mf++)                                                 \
      _Pragma("unroll")                                                            \
      for (int nf = 0; nf < 4; nf++)                                               \
        acc[mf][nf] = __builtin_amdgcn_mfma_f32_16x16x32_bf16(av[mf], bv[nf], acc[mf][nf], 0, 0, 0); \
    __builtin_amdgcn_s_setprio(0);                                                 \
    if ((ks) + 2 < KST) {                                                          \
      asm volatile("s_waitcnt vmcnt(1) lgkmcnt(0)" ::: "memory");                  \
    } else {                                                                       \
      asm volatile("s_waitcnt vmcnt(0) lgkmcnt(0)" ::: "memory");                  \
    }                                                                              \
    __builtin_amdgcn_sched_barrier(0);                                             \
    __builtin_amdgcn_s_barrier();                                                  \
  }

  for (int kk = 0; kk < KST; kk += 2) {
    ITER(kk,     qA, pA);
    ITER(kk + 1, pA, qA);
  }
#undef ITER

  // ---- epilogue smem carved out of Bb (all B reads drained past final barrier) --
  float* eb = (float*)&Bb[0][0];
  float (*sc_part)[8] = (float (*)[8])eb;    // 64 x 8
  float* weight       = eb + 512;            // 64

  // ---- add b_enc, tanh-score partials (per wave: its 64 cols) ----
  float dpv[4], wfv[4], bev[4];
#pragma unroll
  for (int nf = 0; nf < 4; nf++) {
    const int c = wn * 64 + nf * 16 + arow;
    dpv[nf] = dp[b * AD + c];
    wfv[nf] = Wf[c];
    bev[nf] = b_enc[c];
  }
#pragma unroll
  for (int mf = 0; mf < 4; mf++) {
#pragma unroll
    for (int r = 0; r < 4; r++) {
      float p = 0.f;
#pragma unroll
      for (int nf = 0; nf < 4; nf++) {
        float e = acc[mf][nf][r] + bev[nf];
        acc[mf][nf][r] = e;                    // keep enc_proj (+b_enc) for o-accum
        float x = e + dpv[nf];
        float ex = __expf(2.f * x);            // tanh via exp
        float th = 1.f - 2.f / (ex + 1.f);
        p = fmaf(th, wfv[nf], p);
      }
      p += __shfl_xor(p, 1); p += __shfl_xor(p, 2);
      p += __shfl_xor(p, 4); p += __shfl_xor(p, 8);
      if (arow == 0) sc_part[mf * 16 + akg * 4 + r][wn] = p;
    }
  }
  __syncthreads();

  // ---- chunk softmax stats: all 64 rows in wave 0 ----
  if (t < BM) {
    float s = sc_part[t][0] + sc_part[t][1] + sc_part[t][2] + sc_part[t][3]
            + sc_part[t][4] + sc_part[t][5] + sc_part[t][6] + sc_part[t][7];
    raw_scores[(size_t)b * LL + l0 + t] = s;   // raw; finalize normalizes in place
    float m = s;
#pragma unroll
    for (int off = 1; off < 64; off <<= 1) m = fmaxf(m, __shfl_xor(m, off));
    float w = __expf(s - m);
    weight[t] = w;
    float ss = w;
#pragma unroll
    for (int off = 1; off < 64; off <<= 1) ss += __shfl_xor(ss, off);
    if (t == 0) {
      ws_ms[(b * NCH + chunk) * 2]     = m;
      ws_ms[(b * NCH + chunk) * 2 + 1] = ss;
    }
  }
  __syncthreads();

  // ---- o partial: weighted sum of enc_proj over the 64 rows ----
  float wv[4][4];
#pragma unroll
  for (int mf = 0; mf < 4; mf++)
#pragma unroll
    for (int r = 0; r < 4; r++) wv[mf][r] = weight[mf * 16 + akg * 4 + r];
#pragma unroll
  for (int nf = 0; nf < 4; nf++) {
    float cp = 0.f;
#pragma unroll
    for (int mf = 0; mf < 4; mf++)
#pragma unroll
      for (int r = 0; r < 4; r++) cp = fmaf(wv[mf][r], acc[mf][nf][r], cp);
    cp += __shfl_xor(cp, 16);
    cp += __shfl_xor(cp, 32);
    if (lane < 16)
      ws_o[((size_t)b * NCH + chunk) * AD + wn * 64 + nf * 16 + lane] = cp;
  }
}

// ---------------- kernel 2: finalize (merge chunk partials, normalize) ----------
__global__ __launch_bounds__(256) void finalize_kernel(
    const float* __restrict__ ws_ms, const float* __restrict__ ws_o,
    float* __restrict__ out0, float* __restrict__ outS) {
  const int b = blockIdx.x, t = threadIdx.x;
  float ms[NCH], ss[NCH];
  float M = -1e30f;
#pragma unroll
  for (int i = 0; i < NCH; i++) {
    ms[i] = ws_ms[(b * NCH + i) * 2];
    ss[i] = ws_ms[(b * NCH + i) * 2 + 1];
    M = fmaxf(M, ms[i]);
  }
  float S = 0.f, w[NCH];
#pragma unroll
  for (int i = 0; i < NCH; i++) { w[i] = __expf(ms[i] - M); S = fmaf(ss[i], w[i], S); }
  const float invS = 1.f / S;
  for (int c = t; c < AD; c += 256) {
    float a = 0.f;
#pragma unroll
    for (int i = 0; i < NCH; i++) a = fmaf(ws_o[((size_t)b * NCH + i) * AD + c], w[i], a);
    out0[b * AD + c] = a * invS;
  }
  for (int l = t; l < LL; l += 256) {
    float r = outS[(size_t)b * LL + l];
    outS[(size_t)b * LL + l] = __expf(r - M) * invS;
  }
}

extern "C" void kernel_launch(void* const* d_in, const int* in_sizes, int n_in,
                              void* d_out, int out_size, void* d_ws, size_t ws_size,
                              hipStream_t stream) {
  const float* sem    = (const float*)d_in[0];
  const float* dec    = (const float*)d_in[1];
  const float* W_enc  = (const float*)d_in[2];
  const float* b_enc  = (const float*)d_in[3];
  const float* W_dec  = (const float*)d_in[4];
  const float* b_dec  = (const float*)d_in[5];
  const float* W_full = (const float*)d_in[6];
  // d_in[7] = b_full: constant shift, cancels in softmax.

  float* out0 = (float*)d_out;            // att_output [64][512]
  float* outS = out0 + BB * AD;           // att_scores [64][2048]

  char* ws = (char*)d_ws;
  unsigned short* Wb = (unsigned short*)ws;                          // 1 MB bf16 packed W_enc
  float* dpw   = (float*)(ws + (1 << 20));                           // 128 KB dec_proj+b_dec
  float* ws_ms = (float*)(ws + (1 << 20) + (128 << 10));             // 16 KB (m,s) per chunk
  float* ws_o  = (float*)(ws + (1 << 20) + (144 << 10));             // 4 MB o partials

  prep_kernel<<<BB + 128, 512, 0, stream>>>(W_enc, dec, W_dec, b_dec, Wb, dpw);
  dim3 g1(NCH, BB);
  fused_kernel<<<g1, 512, 0, stream>>>(sem, Wb, dpw, b_enc, W_full, outS, ws_ms, ws_o);
  finalize_kernel<<<BB, 256, 0, stream>>>(ws_ms, ws_o, out0, outS);
}